// Round 3
// baseline (10839.589 us; speedup 1.0000x reference)
//
#include <hip/hip_runtime.h>
#include <hip/hip_bf16.h>

// Problem constants (fixed by the reference)
constexpr int NUM_ENT = 100000;
constexpr int NUM_REL = 400;
constexpr int D_IN    = 200;
constexpr int D_OUT   = 400;
constexpr int N_EDGES = 600000;
constexpr int HALF_E  = N_EDGES / 2;
constexpr int BATCH   = 1024;
constexpr float BN_EPS = 1e-5f;

// All tensors f32 (reference dtype).
// Round-1 counters: score_gemm SQ_LDS_BANK_CONFLICT = 9.8e8 (~63% of cycles)
// from 40-way transpose ds_write conflicts.
// Round-3 design: NT-GEMM with NATIVE row-major LDS tiles [128][44]
// (pad 40->44 floats). No LDS transpose at all: staging = coalesced
// ds_write_b128; inner loop = per-row float4-of-k reads + dot4 accumulate.
// Stride-44 + rows tx+16*i gives 8 distinct bank-starts / 16 addrs = 2-way
// reads (free), 4-lane broadcasts otherwise. VALU-bound by design.

constexpr int TS   = 44;   // padded LDS row stride (floats), multiple of 4

// ---------------------------------------------------------------------------
// K0: build W600 = [in_w ; out_w ; Lw] (600 x 400) and its transpose
// WT (400 x 600).  Lw[j][c] = sum_k loop_rel[(j+k)%200] * loop_w[k][c]
// ---------------------------------------------------------------------------
__global__ void build_w600(const float* __restrict__ in_w,
                           const float* __restrict__ out_w,
                           const float* __restrict__ loop_w,
                           const float* __restrict__ loop_rel,
                           float* __restrict__ W600,
                           float* __restrict__ WT) {
    int idx = blockIdx.x * blockDim.x + threadIdx.x;
    if (idx >= 600 * D_OUT) return;
    int k = idx / D_OUT, c = idx % D_OUT;
    float v;
    if (k < 200) {
        v = in_w[k * D_OUT + c];
    } else if (k < 400) {
        v = out_w[(k - 200) * D_OUT + c];
    } else {
        int j = k - 400;
        float acc = 0.f;
        for (int kk = 0; kk < D_IN; ++kk) {
            int idx2 = j + kk;
            if (idx2 >= D_IN) idx2 -= D_IN;
            acc += loop_rel[idx2] * loop_w[kk * D_OUT + c];
        }
        v = acc;
    }
    W600[idx] = v;
    WT[(size_t)c * 600 + k] = v;
}

// ---------------------------------------------------------------------------
// K1: per-edge ccorr + scatter into P (NUM_ENT x 400).
//   4 edges per 256-thread block (one per wave). Lanes 0..49 each produce
//   4 consecutive output columns (k0 = 4*lane). b staged duplicated in LDS
//   (no modulo); j unrolled by 8 with a 12-float sliding b-window.
//   ccorr(a,b)[k] = sum_j a[j] * b[(j+k) % 200]
// ---------------------------------------------------------------------------
__global__ __launch_bounds__(256) void edge_kernel(
        const float* __restrict__ ent, const float* __restrict__ rel,
        const int* __restrict__ src, const int* __restrict__ dst,
        const int* __restrict__ etype, const float* __restrict__ norm,
        float* __restrict__ P) {
    __shared__ __align__(16) float a_s[4][D_IN];        // 4 x 200
    __shared__ __align__(16) float b_s[4][2 * D_IN];    // 4 x 400 (duplicated)
    const int w    = threadIdx.x >> 6;
    const int lane = threadIdx.x & 63;
    const int e    = blockIdx.x * 4 + w;       // grid = N_EDGES/4 exactly
    const int s  = src[e];
    const int ty = etype[e];

    if (lane < 50) {
        *reinterpret_cast<float4*>(&a_s[w][lane * 4]) =
            *reinterpret_cast<const float4*>(&ent[(size_t)s * D_IN + lane * 4]);
    }
    for (int t4 = lane; t4 < 100; t4 += 64) {
        int o = 4 * t4;
        if (o >= D_IN) o -= D_IN;
        *reinterpret_cast<float4*>(&b_s[w][4 * t4]) =
            *reinterpret_cast<const float4*>(&rel[(size_t)ty * D_IN + o]);
    }
    __syncthreads();

    if (lane < 50) {
        const int k0 = lane * 4;
        float acc0 = 0.f, acc1 = 0.f, acc2 = 0.f, acc3 = 0.f;
        for (int j = 0; j < D_IN; j += 8) {
            float4 aA = *reinterpret_cast<const float4*>(&a_s[w][j]);
            float4 aB = *reinterpret_cast<const float4*>(&a_s[w][j + 4]);
            float4 b0 = *reinterpret_cast<const float4*>(&b_s[w][j + k0]);
            float4 b1 = *reinterpret_cast<const float4*>(&b_s[w][j + k0 + 4]);
            float4 b2 = *reinterpret_cast<const float4*>(&b_s[w][j + k0 + 8]);
            const float aw[8]  = {aA.x, aA.y, aA.z, aA.w,
                                  aB.x, aB.y, aB.z, aB.w};
            const float bw[12] = {b0.x, b0.y, b0.z, b0.w,
                                  b1.x, b1.y, b1.z, b1.w,
                                  b2.x, b2.y, b2.z, b2.w};
            #pragma unroll
            for (int m = 0; m < 8; ++m) {
                acc0 += aw[m] * bw[m + 0];
                acc1 += aw[m] * bw[m + 1];
                acc2 += aw[m] * bw[m + 2];
                acc3 += aw[m] * bw[m + 3];
            }
        }
        const float nv = norm[e];
        float* outp = P + (size_t)dst[e] * 400 + ((e < HALF_E) ? 0 : 200) + k0;
        atomicAdd(outp + 0, nv * acc0);
        atomicAdd(outp + 1, nv * acc1);
        atomicAdd(outp + 2, nv * acc2);
        atomicAdd(outp + 3, nv * acc3);
    }
}

// ---------------------------------------------------------------------------
// K2: x = A @ W600 / 3 + bias, A = [P | ent] (K=600), via NT form:
// x[r][c] = dot(Arow[r][:], WT[c][:]). Only emits column sum / sumsq.
// Tile 128 rows x 128 cols, K-chunk 40, 8x8/thread (rows tx+16i, cols
// tyy+16j). Native row-major LDS tiles, stride 44. grid = (782, 4).
// ---------------------------------------------------------------------------
__global__ __launch_bounds__(256) void x_gemm_stats(
        const float* __restrict__ P, const float* __restrict__ ent,
        const float* __restrict__ WT, const float* __restrict__ bias,
        float* __restrict__ sum_g, float* __restrict__ ssq_g) {
    __shared__ __align__(16) float As[128 * TS];
    __shared__ __align__(16) float Bs[128 * TS];
    __shared__ float lsum[128], lssq[128];
    const int tid = threadIdx.x;
    const int tx  = tid & 15;     // row group
    const int tyy = tid >> 4;     // col group
    const int row0 = blockIdx.x * 128;
    const int col0 = blockIdx.y * 128;
    float acc[8][8] = {};

    for (int kc = 0; kc < 600; kc += 40) {
        const bool fromP = (kc < 400);
        #pragma unroll
        for (int i = 0; i < 5; ++i) {
            int fi = tid + 256 * i;              // 0..1279 = 128 rows x 10 f4
            int row = fi / 10, kb = fi % 10;
            int r = row0 + row;
            float4 v = make_float4(0.f, 0.f, 0.f, 0.f);
            if (r < NUM_ENT)
                v = fromP
                  ? *reinterpret_cast<const float4*>(&P[(size_t)r * 400 + kc + 4 * kb])
                  : *reinterpret_cast<const float4*>(&ent[(size_t)r * D_IN + (kc - 400) + 4 * kb]);
            *reinterpret_cast<float4*>(&As[row * TS + 4 * kb]) = v;
        }
        #pragma unroll
        for (int i = 0; i < 5; ++i) {
            int fi = tid + 256 * i;
            int col = fi / 10, kb = fi % 10;
            int c = col0 + col;
            float4 v = make_float4(0.f, 0.f, 0.f, 0.f);
            if (c < D_OUT)
                v = *reinterpret_cast<const float4*>(&WT[(size_t)c * 600 + kc + 4 * kb]);
            *reinterpret_cast<float4*>(&Bs[col * TS + 4 * kb]) = v;
        }
        __syncthreads();
        #pragma unroll
        for (int kb = 0; kb < 10; ++kb) {
            float4 a4[8], b4[8];
            #pragma unroll
            for (int i = 0; i < 8; ++i)
                a4[i] = *reinterpret_cast<const float4*>(&As[(tx + 16 * i) * TS + 4 * kb]);
            #pragma unroll
            for (int j = 0; j < 8; ++j)
                b4[j] = *reinterpret_cast<const float4*>(&Bs[(tyy + 16 * j) * TS + 4 * kb]);
            #pragma unroll
            for (int i = 0; i < 8; ++i)
                #pragma unroll
                for (int j = 0; j < 8; ++j)
                    acc[i][j] += a4[i].x * b4[j].x + a4[i].y * b4[j].y
                               + a4[i].z * b4[j].z + a4[i].w * b4[j].w;
        }
        __syncthreads();
    }

    if (tid < 128) { lsum[tid] = 0.f; lssq[tid] = 0.f; }
    __syncthreads();
    #pragma unroll
    for (int j = 0; j < 8; ++j) {
        int c = col0 + tyy + 16 * j;
        if (c < D_OUT) {
            float bv = bias[c];
            float s = 0.f, q = 0.f;
            #pragma unroll
            for (int i = 0; i < 8; ++i) {
                int row = row0 + tx + 16 * i;
                if (row < NUM_ENT) {
                    float xv = acc[i][j] * (1.f / 3.f) + bv;
                    s += xv;
                    q += xv * xv;
                }
            }
            atomicAdd(&lsum[tyy + 16 * j], s);
            atomicAdd(&lssq[tyy + 16 * j], q);
        }
    }
    __syncthreads();
    if (tid < 128) {
        int c = col0 + tid;
        if (c < D_OUT) {
            atomicAdd(&sum_g[c], lsum[tid]);
            atomicAdd(&ssq_g[c], lssq[tid]);
        }
    }
}

// ---------------------------------------------------------------------------
// K3: finalize BN: scale = gamma * rsqrt(var+eps), shift = beta - mean*scale
// ---------------------------------------------------------------------------
__global__ void bn_finalize(const float* __restrict__ sum_g,
                            const float* __restrict__ ssq_g,
                            const float* __restrict__ gamma,
                            const float* __restrict__ beta,
                            float* __restrict__ scale,
                            float* __restrict__ shift) {
    int c = blockIdx.x * blockDim.x + threadIdx.x;
    if (c < D_OUT) {
        float m = sum_g[c] * (1.f / (float)NUM_ENT);
        float v = ssq_g[c] * (1.f / (float)NUM_ENT) - m * m;
        float rs = rsqrtf(v + BN_EPS);
        float sc = gamma[c] * rs;
        scale[c] = sc;
        shift[c] = beta[c] - m * sc;
    }
}

// ---------------------------------------------------------------------------
// K4: R = rel_emb @ w_rel  (400 x 400)
// ---------------------------------------------------------------------------
__global__ void rel_gemm(const float* __restrict__ rel,
                         const float* __restrict__ w_rel,
                         float* __restrict__ R) {
    int idx = blockIdx.x * blockDim.x + threadIdx.x;
    if (idx >= NUM_REL * D_OUT) return;
    int i = idx / D_OUT, c = idx % D_OUT;
    float acc = 0.f;
    for (int k = 0; k < D_IN; ++k)
        acc += rel[(size_t)i * D_IN + k] * w_rel[(size_t)k * D_OUT + c];
    R[idx] = acc;
}

// ---------------------------------------------------------------------------
// K5: recompute x for the 1024 gathered head rows, apply BN+tanh, times
// rela row -> OBJ (1024 x 400). Uses k-major W600 (coalesced across c).
// ---------------------------------------------------------------------------
__global__ __launch_bounds__(256) void obj_kernel(
        const float* __restrict__ P, const float* __restrict__ ent,
        const float* __restrict__ W, const float* __restrict__ bias,
        const float* __restrict__ scale, const float* __restrict__ shift,
        const float* __restrict__ R, const int* __restrict__ triples,
        float* __restrict__ OBJ) {
    __shared__ float As[600];
    int t = blockIdx.x;
    int h  = triples[t * 3 + 0];
    int rr = triples[t * 3 + 1];
    int tid = threadIdx.x;
    for (int k = tid; k < 600; k += 256)
        As[k] = (k < 400) ? P[(size_t)h * 400 + k]
                          : ent[(size_t)h * D_IN + (k - 400)];
    __syncthreads();
    for (int c = tid; c < D_OUT; c += 256) {
        float acc = 0.f;
        for (int k = 0; k < 600; ++k)
            acc += As[k] * W[(size_t)k * D_OUT + c];
        float xv = acc * (1.f / 3.f) + bias[c];
        float nv = tanhf(xv * scale[c] + shift[c]);
        OBJ[(size_t)t * D_OUT + c] = nv * R[(size_t)rr * D_OUT + c];
    }
}

// ---------------------------------------------------------------------------
// K6: score = sigmoid(OBJ @ emb_ent_w^T + ent_bias), out f32 (1024 x 100000)
// NT form: both operands row-major over K=D_OUT. Tile 128 n x 128 t,
// K-chunk 40, 8x8/thread. Native row-major LDS, stride 44. grid = (782, 8).
// Epilogue: scalar dword stores (n = tx+16i are 16-consecutive runs per
// tyy group -> 64B segments, acceptably coalesced; stores ~65us of HBM).
// ---------------------------------------------------------------------------
__global__ __launch_bounds__(256) void score_gemm(
        const float* __restrict__ emb, const float* __restrict__ OBJ,
        const float* __restrict__ ent_bias, float* __restrict__ out) {
    __shared__ __align__(16) float As[128 * TS];   // emb rows (n)
    __shared__ __align__(16) float Bs[128 * TS];   // OBJ rows (t)
    const int tid = threadIdx.x;
    const int tx  = tid & 15;     // n group
    const int tyy = tid >> 4;     // t group
    const int n0 = blockIdx.x * 128;
    const int t0 = blockIdx.y * 128;
    float acc[8][8] = {};

    for (int kc = 0; kc < D_OUT; kc += 40) {
        #pragma unroll
        for (int i = 0; i < 5; ++i) {
            int fi = tid + 256 * i;              // 0..1279
            int row = fi / 10, kb = fi % 10;
            int n = n0 + row;
            float4 v = make_float4(0.f, 0.f, 0.f, 0.f);
            if (n < NUM_ENT)
                v = *reinterpret_cast<const float4*>(&emb[(size_t)n * D_OUT + kc + 4 * kb]);
            *reinterpret_cast<float4*>(&As[row * TS + 4 * kb]) = v;
        }
        #pragma unroll
        for (int i = 0; i < 5; ++i) {
            int fi = tid + 256 * i;
            int trow = fi / 10, kb = fi % 10;
            float4 v = *reinterpret_cast<const float4*>(
                &OBJ[(size_t)(t0 + trow) * D_OUT + kc + 4 * kb]);
            *reinterpret_cast<float4*>(&Bs[trow * TS + 4 * kb]) = v;
        }
        __syncthreads();
        #pragma unroll
        for (int kb = 0; kb < 10; ++kb) {
            float4 a4[8], b4[8];
            #pragma unroll
            for (int i = 0; i < 8; ++i)
                a4[i] = *reinterpret_cast<const float4*>(&As[(tx + 16 * i) * TS + 4 * kb]);
            #pragma unroll
            for (int j = 0; j < 8; ++j)
                b4[j] = *reinterpret_cast<const float4*>(&Bs[(tyy + 16 * j) * TS + 4 * kb]);
            #pragma unroll
            for (int i = 0; i < 8; ++i)
                #pragma unroll
                for (int j = 0; j < 8; ++j)
                    acc[i][j] += a4[i].x * b4[j].x + a4[i].y * b4[j].y
                               + a4[i].z * b4[j].z + a4[i].w * b4[j].w;
        }
        __syncthreads();
    }

    float eb[8];
    #pragma unroll
    for (int i = 0; i < 8; ++i) {
        int n = n0 + tx + 16 * i;
        eb[i] = (n < NUM_ENT) ? ent_bias[n] : 0.f;
    }
    #pragma unroll
    for (int j = 0; j < 8; ++j) {
        int t = t0 + tyy + 16 * j;
        #pragma unroll
        for (int i = 0; i < 8; ++i) {
            int n = n0 + tx + 16 * i;
            if (n < NUM_ENT) {
                float logit = acc[i][j] + eb[i];
                out[(size_t)t * NUM_ENT + n] = 1.f / (1.f + __expf(-logit));
            }
        }
    }
}

// ---------------------------------------------------------------------------
extern "C" void kernel_launch(void* const* d_in, const int* in_sizes, int n_in,
                              void* d_out, int out_size, void* d_ws, size_t ws_size,
                              hipStream_t stream) {
    const float* ent      = (const float*)d_in[0];
    const float* rel      = (const float*)d_in[1];
    const float* in_w     = (const float*)d_in[2];
    const float* out_w    = (const float*)d_in[3];
    const float* loop_w   = (const float*)d_in[4];
    const float* w_rel    = (const float*)d_in[5];
    const float* loop_rel = (const float*)d_in[6];
    const float* bias_w   = (const float*)d_in[7];
    const float* gamma    = (const float*)d_in[8];
    const float* beta     = (const float*)d_in[9];
    const float* emb      = (const float*)d_in[10];
    const float* ent_bias = (const float*)d_in[11];
    const int*   src      = (const int*)d_in[12];
    const int*   dst      = (const int*)d_in[13];
    const int*   etype    = (const int*)d_in[14];
    const float* norm     = (const float*)d_in[15];
    const int*   triples  = (const int*)d_in[16];
    float* out            = (float*)d_out;

    float* ws_f  = (float*)d_ws;
    float* P     = ws_f;                       // 100000*400 f (160 MB)
    float* W600  = P + (size_t)NUM_ENT * 400;  // 600*400
    float* WT    = W600 + 600 * D_OUT;         // 400*600
    float* Rmat  = WT + 600 * D_OUT;           // 400*400
    float* OBJ   = Rmat + NUM_REL * D_OUT;     // 1024*400
    float* SUM   = OBJ + (size_t)BATCH * D_OUT;
    float* SSQ   = SUM + D_OUT;
    float* SCALE = SSQ + D_OUT;
    float* SHIFT = SCALE + D_OUT;

    hipMemsetAsync(P, 0, (size_t)NUM_ENT * 400 * sizeof(float), stream);
    hipMemsetAsync(SUM, 0, 2 * D_OUT * sizeof(float), stream);

    build_w600<<<(600 * D_OUT + 255) / 256, 256, 0, stream>>>(
        in_w, out_w, loop_w, loop_rel, W600, WT);

    edge_kernel<<<N_EDGES / 4, 256, 0, stream>>>(ent, rel, src, dst, etype, norm, P);

    dim3 gx((NUM_ENT + 127) / 128, (D_OUT + 127) / 128);
    x_gemm_stats<<<gx, 256, 0, stream>>>(P, ent, WT, bias_w, SUM, SSQ);

    bn_finalize<<<2, 256, 0, stream>>>(SUM, SSQ, gamma, beta, SCALE, SHIFT);

    rel_gemm<<<(NUM_REL * D_OUT + 255) / 256, 256, 0, stream>>>(rel, w_rel, Rmat);

    obj_kernel<<<BATCH, 256, 0, stream>>>(P, ent, W600, bias_w, SCALE, SHIFT,
                                          Rmat, triples, OBJ);

    dim3 gs((NUM_ENT + 127) / 128, BATCH / 128);
    score_gemm<<<gs, 256, 0, stream>>>(emb, OBJ, ent_bias, out);
}